// Round 3
// baseline (279.266 us; speedup 1.0000x reference)
//
#include <hip/hip_runtime.h>

// Windowed MHA, B=16 C=128 H=W=128, WINDOW=64, heads=4, d=32.
// 4096 blocks x 512 threads (8 waves; wave = (head w, token-half h)).
// bf16 MFMA 16x16x32. Swapped QK^T (scores^T = mfma(K,Q)) so softmax is
// register-resident with k in the reg index; P per-wave in LDS (no barrier).
// LDS 48KB -> 3 blocks/CU.

typedef __attribute__((ext_vector_type(8))) short bf16x8;
typedef __attribute__((ext_vector_type(4))) float f32x4;

__device__ __forceinline__ ushort f2bf(float f) {
    unsigned u = __float_as_uint(f);
    u += 0x7FFF + ((u >> 16) & 1);          // RNE
    return (ushort)(u >> 16);
}
__device__ __forceinline__ unsigned pk2(float a, float b) {
    return (unsigned)f2bf(a) | ((unsigned)f2bf(b) << 16);
}

__global__ void wconv(const float* __restrict__ Wq, const float* __restrict__ Wk,
                      const float* __restrict__ Wv, ushort* __restrict__ out) {
    int i = blockIdx.x * 256 + threadIdx.x;        // 16384 per matrix
    out[i]         = f2bf(Wq[i]);
    out[16384 + i] = f2bf(Wk[i]);
    out[32768 + i] = f2bf(Wv[i]);
}

__global__ __launch_bounds__(512, 6)
void attn_win(const float* __restrict__ x, const ushort* __restrict__ wbf,
              const float* __restrict__ bq, const float* __restrict__ bk,
              const float* __restrict__ bv, const float* __restrict__ Bb,
              float* __restrict__ out) {
    __shared__ __align__(16) char smem[49152];
    // R0 [0,16K): sX (staging) -> sVt after B1.5
    // R1 [16K,32K): sQ   R2 [32K,48K): sK
    // sP (4 heads x 8K) aliases R1+R2 after B3; per-wave-private rows.
    char* sX  = smem;
    char* sVt = smem;
    char* sQ  = smem + 16384;
    char* sK  = smem + 32768;
    char* sP  = smem + 16384;

    const int tid = threadIdx.x;
    const int wid = tid >> 6;        // 0..7
    const int w = wid & 3;           // head
    const int h = wid >> 2;          // token half (0..1)
    const int l = tid & 63;
    const int lr = l & 15;
    const int lg = (l >> 4) & 3;
    const int blk = blockIdx.x;
    const int b = blk >> 8, n = blk & 255;
    const long xbase = (long)b * 128 * 16384 + n * 64;

    // ---- stage X: channel-pair loads, packed ds_write_b32 ----
    #pragma unroll
    for (int it = 0; it < 2; ++it) {
        int idx = it * 512 + tid;            // 1024 (cpair,t4) items
        int cp = idx >> 4, t4 = idx & 15;
        const float* px = x + xbase + (long)(2 * cp) * 16384 + t4 * 4;
        float4 v0 = *(const float4*)(px);
        float4 v1 = *(const float4*)(px + 16384);
        float a0[4] = {v0.x, v0.y, v0.z, v0.w};
        float a1[4] = {v1.x, v1.y, v1.z, v1.w};
        #pragma unroll
        for (int jj = 0; jj < 4; ++jj) {
            int t = t4 * 4 + jj;
            *(unsigned*)(sX + t * 256 + ((4 * cp) ^ ((t & 7) << 4))) = pk2(a0[jj], a1[jj]);
        }
    }
    __syncthreads();   // B1

    // ---- A-fragments of X for this wave's 32 tokens ----
    bf16x8 aX[2][4];
    #pragma unroll
    for (int tmi = 0; tmi < 2; ++tmi) {
        int row = 32 * h + 16 * tmi + lr;
        #pragma unroll
        for (int kk = 0; kk < 4; ++kk) {
            int colb = (8 * lg + 32 * kk) * 2;
            aX[tmi][kk] = *(const bf16x8*)(sX + row * 256 + (colb ^ ((row & 7) << 4)));
        }
    }
    __syncthreads();   // B1.5: all aX loaded before sVt overwrites sX

    // ---- projections: tokens 32h..+31, out-ch 32w..+31 ----
    const float* biases[3] = {bq, bk, bv};
    #pragma unroll
    for (int p = 0; p < 3; ++p) {
        const ushort* wp = wbf + p * 16384;
        bf16x8 bW[2][4];
        #pragma unroll
        for (int tn = 0; tn < 2; ++tn) {
            int orow = 32 * w + 16 * tn + lr;
            #pragma unroll
            for (int kk = 0; kk < 4; ++kk)
                bW[tn][kk] = *(const bf16x8*)(wp + orow * 128 + 8 * lg + 32 * kk);
        }
        f32x4 acc[2][2];
        #pragma unroll
        for (int tn = 0; tn < 2; ++tn) {
            float bias = biases[p][32 * w + 16 * tn + lr];
            #pragma unroll
            for (int tmi = 0; tmi < 2; ++tmi)
                acc[tmi][tn] = (f32x4){bias, bias, bias, bias};
        }
        #pragma unroll
        for (int kk = 0; kk < 4; ++kk)
            #pragma unroll
            for (int tmi = 0; tmi < 2; ++tmi)
                #pragma unroll
                for (int tn = 0; tn < 2; ++tn)
                    acc[tmi][tn] = __builtin_amdgcn_mfma_f32_16x16x32_bf16(
                        aX[tmi][kk], bW[tn][kk], acc[tmi][tn], 0, 0, 0);
        if (p < 2) {
            // D: row tok = 32h+16tmi+4lg+r, col ch = 32w+16tn+lr -> scalar b16
            char* dst = (p == 0) ? sQ : sK;
            #pragma unroll
            for (int tmi = 0; tmi < 2; ++tmi)
                #pragma unroll
                for (int tn = 0; tn < 2; ++tn)
                    #pragma unroll
                    for (int r = 0; r < 4; ++r) {
                        int row = 32 * h + 16 * tmi + 4 * lg + r;
                        int col = 32 * w + 16 * tn + lr;
                        *(ushort*)(dst + row * 256 + ((col * 2) ^ ((row & 7) << 4)))
                            = f2bf(acc[tmi][tn][r]);
                    }
        } else {
            // V transposed sVt[c][tok]: r spans 4 consecutive tokens -> packed b64
            #pragma unroll
            for (int tmi = 0; tmi < 2; ++tmi)
                #pragma unroll
                for (int tn = 0; tn < 2; ++tn) {
                    int crow = 32 * w + 16 * tn + lr;
                    int tok0 = 32 * h + 16 * tmi + 4 * lg;
                    uint2 pk;
                    pk.x = pk2(acc[tmi][tn][0], acc[tmi][tn][1]);
                    pk.y = pk2(acc[tmi][tn][2], acc[tmi][tn][3]);
                    *(uint2*)(sVt + crow * 128 + ((2 * tok0) ^ ((crow & 7) << 4))) = pk;
                }
        }
    }
    __syncthreads();   // B2

    // ---- scores^T = mfma(A=K, B=Q): D[k=16tm+4lg+r][q=32h+16tq+lr] ----
    bf16x8 aK[4], bQ[2];
    const int colqk = (32 * w + 8 * lg) * 2;
    #pragma unroll
    for (int tm = 0; tm < 4; ++tm) {
        int row = 16 * tm + lr;
        aK[tm] = *(const bf16x8*)(sK + row * 256 + (colqk ^ ((row & 7) << 4)));
    }
    #pragma unroll
    for (int tq = 0; tq < 2; ++tq) {
        int row = 32 * h + 16 * tq + lr;
        bQ[tq] = *(const bf16x8*)(sQ + row * 256 + (colqk ^ ((row & 7) << 4)));
    }
    f32x4 sc[4][2];
    #pragma unroll
    for (int tm = 0; tm < 4; ++tm)
        #pragma unroll
        for (int tq = 0; tq < 2; ++tq) {
            sc[tm][tq] = (f32x4){0.f, 0.f, 0.f, 0.f};
            sc[tm][tq] = __builtin_amdgcn_mfma_f32_16x16x32_bf16(
                aK[tm], bQ[tq], sc[tm][tq], 0, 0, 0);
        }

    // ---- softmax: k lives in (tm,r) in-lane (16 vals) + lg across lanes ----
    const float scale = 0.17677669529663687f;   // 1/sqrt(32)
    const float L2E = 1.4426950408889634f;
    #pragma unroll
    for (int tq = 0; tq < 2; ++tq) {
        int q = 32 * h + 16 * tq + lr;
        #pragma unroll
        for (int tm = 0; tm < 4; ++tm) {
            float4 bb = *(const float4*)(Bb + q * 64 + 16 * tm + 4 * lg);
            sc[tm][tq][0] = sc[tm][tq][0] * scale + bb.x;
            sc[tm][tq][1] = sc[tm][tq][1] * scale + bb.y;
            sc[tm][tq][2] = sc[tm][tq][2] * scale + bb.z;
            sc[tm][tq][3] = sc[tm][tq][3] * scale + bb.w;
        }
        float mx = sc[0][tq][0];
        #pragma unroll
        for (int tm = 0; tm < 4; ++tm)
            #pragma unroll
            for (int r = 0; r < 4; ++r)
                mx = fmaxf(mx, sc[tm][tq][r]);
        mx = fmaxf(mx, __shfl_xor(mx, 16));
        mx = fmaxf(mx, __shfl_xor(mx, 32));
        float s = 0.f;
        #pragma unroll
        for (int tm = 0; tm < 4; ++tm)
            #pragma unroll
            for (int r = 0; r < 4; ++r) {
                float e = exp2f((sc[tm][tq][r] - mx) * L2E);
                sc[tm][tq][r] = e;
                s += e;
            }
        s += __shfl_xor(s, 16);
        s += __shfl_xor(s, 32);
        float rs = 1.0f / s;
        #pragma unroll
        for (int tm = 0; tm < 4; ++tm)
            #pragma unroll
            for (int r = 0; r < 4; ++r)
                sc[tm][tq][r] *= rs;        // normalize at source
    }
    __syncthreads();   // B3: sQ/sK frag reads done before sP overwrite

    // ---- P (normalized, bf16) -> per-wave-private sP rows, packed b64 ----
    char* sPw = sP + w * 8192;
    #pragma unroll
    for (int tm = 0; tm < 4; ++tm)
        #pragma unroll
        for (int tq = 0; tq < 2; ++tq) {
            int q = 32 * h + 16 * tq + lr;
            int k0 = 16 * tm + 4 * lg;
            uint2 pk;
            pk.x = pk2(sc[tm][tq][0], sc[tm][tq][1]);
            pk.y = pk2(sc[tm][tq][2], sc[tm][tq][3]);
            *(uint2*)(sPw + q * 128 + ((2 * k0) ^ ((q & 7) << 4))) = pk;
        }
    // same-wave write->read: no barrier needed (lgkmcnt ordering by compiler)

    // ---- out = P . V : q 32 (2 tiles), d 32 (2 tiles), K = 64 keys ----
    f32x4 o[2][2];
    #pragma unroll
    for (int tm2 = 0; tm2 < 2; ++tm2)
        #pragma unroll
        for (int tn = 0; tn < 2; ++tn)
            o[tm2][tn] = (f32x4){0.f, 0.f, 0.f, 0.f};
    #pragma unroll
    for (int kk = 0; kk < 2; ++kk) {
        bf16x8 aP[2], bV[2];
        int colk = (32 * kk + 8 * lg) * 2;
        #pragma unroll
        for (int tm2 = 0; tm2 < 2; ++tm2) {
            int q = 32 * h + 16 * tm2 + lr;
            aP[tm2] = *(const bf16x8*)(sPw + q * 128 + (colk ^ ((q & 7) << 4)));
        }
        #pragma unroll
        for (int tn = 0; tn < 2; ++tn) {
            int cc = 32 * w + 16 * tn + lr;
            bV[tn] = *(const bf16x8*)(sVt + cc * 128 + (colk ^ ((cc & 7) << 4)));
        }
        #pragma unroll
        for (int tm2 = 0; tm2 < 2; ++tm2)
            #pragma unroll
            for (int tn = 0; tn < 2; ++tn)
                o[tm2][tn] = __builtin_amdgcn_mfma_f32_16x16x32_bf16(
                    aP[tm2], bV[tn], o[tm2][tn], 0, 0, 0);
    }

    // ---- direct coalesced float4 stores (4 consecutive tokens per reg) ----
    #pragma unroll
    for (int tm2 = 0; tm2 < 2; ++tm2)
        #pragma unroll
        for (int tn = 0; tn < 2; ++tn) {
            int ch = 32 * w + 16 * tn + lr;
            int tok = 32 * h + 16 * tm2 + 4 * lg;
            float4 ov;
            ov.x = o[tm2][tn][0];
            ov.y = o[tm2][tn][1];
            ov.z = o[tm2][tn][2];
            ov.w = o[tm2][tn][3];
            *(float4*)(out + xbase + (long)ch * 16384 + tok) = ov;
        }
}

extern "C" void kernel_launch(void* const* d_in, const int* in_sizes, int n_in,
                              void* d_out, int out_size, void* d_ws, size_t ws_size,
                              hipStream_t stream) {
    const float* x  = (const float*)d_in[0];
    const float* Wq = (const float*)d_in[1];
    const float* bq = (const float*)d_in[2];
    const float* Wk = (const float*)d_in[3];
    const float* bk = (const float*)d_in[4];
    const float* Wv = (const float*)d_in[5];
    const float* bv = (const float*)d_in[6];
    const float* Bb = (const float*)d_in[7];
    float* out = (float*)d_out;
    ushort* wbf = (ushort*)d_ws;   // 3 x 128x128 bf16 = 96 KB

    wconv<<<64, 256, 0, stream>>>(Wq, Wk, Wv, wbf);
    attn_win<<<4096, 512, 0, stream>>>(x, wbf, bq, bk, bv, Bb, out);
}

// Round 4
// 146.805 us; speedup vs baseline: 1.9023x; 1.9023x over previous
//
#include <hip/hip_runtime.h>

// Windowed MHA, B=16 C=128 H=W=128, WINDOW=64, heads=4, d=32.
// 4096 blocks x 512 threads (8 waves; wave = (head w, token-half h)).
// bf16 MFMA 16x16x32. Swapped QK^T (scores^T = mfma(K,Q)) so softmax is
// register-resident with k in the reg index; P per-wave in LDS (no barrier).
// LDS 48KB. launch_bounds(512,4): cap 128 VGPR — round-3's (512,6) forced
// a 40-VGPR spill disaster (FETCH 71->308MB, WRITE 188->594MB).

typedef __attribute__((ext_vector_type(8))) short bf16x8;
typedef __attribute__((ext_vector_type(4))) float f32x4;

__device__ __forceinline__ ushort f2bf(float f) {
    unsigned u = __float_as_uint(f);
    u += 0x7FFF + ((u >> 16) & 1);          // RNE
    return (ushort)(u >> 16);
}
__device__ __forceinline__ unsigned pk2(float a, float b) {
    return (unsigned)f2bf(a) | ((unsigned)f2bf(b) << 16);
}

__global__ void wconv(const float* __restrict__ Wq, const float* __restrict__ Wk,
                      const float* __restrict__ Wv, ushort* __restrict__ out) {
    int i = blockIdx.x * 256 + threadIdx.x;        // 16384 per matrix
    out[i]         = f2bf(Wq[i]);
    out[16384 + i] = f2bf(Wk[i]);
    out[32768 + i] = f2bf(Wv[i]);
}

__global__ __launch_bounds__(512, 4)
void attn_win(const float* __restrict__ x, const ushort* __restrict__ wbf,
              const float* __restrict__ bq, const float* __restrict__ bk,
              const float* __restrict__ bv, const float* __restrict__ Bb,
              float* __restrict__ out) {
    __shared__ __align__(16) char smem[49152];
    // R0 [0,16K): sX (staging) -> sVt after B1.5
    // R1 [16K,32K): sQ   R2 [32K,48K): sK
    // sP (4 heads x 8K) aliases R1+R2 after B3; per-wave-private rows.
    char* sX  = smem;
    char* sVt = smem;
    char* sQ  = smem + 16384;
    char* sK  = smem + 32768;
    char* sP  = smem + 16384;

    const int tid = threadIdx.x;
    const int wid = tid >> 6;        // 0..7
    const int w = wid & 3;           // head
    const int h = wid >> 2;          // token half (0..1)
    const int l = tid & 63;
    const int lr = l & 15;
    const int lg = (l >> 4) & 3;
    const int blk = blockIdx.x;
    const int b = blk >> 8, n = blk & 255;
    const long xbase = (long)b * 128 * 16384 + n * 64;

    // ---- stage X: channel-pair loads, packed ds_write_b32 ----
    #pragma unroll
    for (int it = 0; it < 2; ++it) {
        int idx = it * 512 + tid;            // 1024 (cpair,t4) items
        int cp = idx >> 4, t4 = idx & 15;
        const float* px = x + xbase + (long)(2 * cp) * 16384 + t4 * 4;
        float4 v0 = *(const float4*)(px);
        float4 v1 = *(const float4*)(px + 16384);
        float a0[4] = {v0.x, v0.y, v0.z, v0.w};
        float a1[4] = {v1.x, v1.y, v1.z, v1.w};
        #pragma unroll
        for (int jj = 0; jj < 4; ++jj) {
            int t = t4 * 4 + jj;
            *(unsigned*)(sX + t * 256 + ((4 * cp) ^ ((t & 7) << 4))) = pk2(a0[jj], a1[jj]);
        }
    }
    __syncthreads();   // B1

    // ---- A-fragments of X for this wave's 32 tokens ----
    bf16x8 aX[2][4];
    #pragma unroll
    for (int tmi = 0; tmi < 2; ++tmi) {
        int row = 32 * h + 16 * tmi + lr;
        #pragma unroll
        for (int kk = 0; kk < 4; ++kk) {
            int colb = (8 * lg + 32 * kk) * 2;
            aX[tmi][kk] = *(const bf16x8*)(sX + row * 256 + (colb ^ ((row & 7) << 4)));
        }
    }
    __syncthreads();   // B1.5: all aX loaded before sVt overwrites sX

    // ---- projections: tokens 32h..+31, out-ch 32w..+31 ----
    const float* biases[3] = {bq, bk, bv};
    #pragma unroll
    for (int p = 0; p < 3; ++p) {
        const ushort* wp = wbf + p * 16384;
        f32x4 acc[2][2];
        #pragma unroll
        for (int tn = 0; tn < 2; ++tn) {
            float bias = biases[p][32 * w + 16 * tn + lr];
            #pragma unroll
            for (int tmi = 0; tmi < 2; ++tmi)
                acc[tmi][tn] = (f32x4){bias, bias, bias, bias};
        }
        // bW loaded per-kk to keep peak VGPR pressure low (spill avoidance)
        #pragma unroll
        for (int kk = 0; kk < 4; ++kk) {
            bf16x8 bW[2];
            #pragma unroll
            for (int tn = 0; tn < 2; ++tn) {
                int orow = 32 * w + 16 * tn + lr;
                bW[tn] = *(const bf16x8*)(wp + orow * 128 + 8 * lg + 32 * kk);
            }
            #pragma unroll
            for (int tmi = 0; tmi < 2; ++tmi)
                #pragma unroll
                for (int tn = 0; tn < 2; ++tn)
                    acc[tmi][tn] = __builtin_amdgcn_mfma_f32_16x16x32_bf16(
                        aX[tmi][kk], bW[tn], acc[tmi][tn], 0, 0, 0);
        }
        if (p < 2) {
            // D: row tok = 32h+16tmi+4lg+r, col ch = 32w+16tn+lr -> scalar b16
            char* dst = (p == 0) ? sQ : sK;
            #pragma unroll
            for (int tmi = 0; tmi < 2; ++tmi)
                #pragma unroll
                for (int tn = 0; tn < 2; ++tn)
                    #pragma unroll
                    for (int r = 0; r < 4; ++r) {
                        int row = 32 * h + 16 * tmi + 4 * lg + r;
                        int col = 32 * w + 16 * tn + lr;
                        *(ushort*)(dst + row * 256 + ((col * 2) ^ ((row & 7) << 4)))
                            = f2bf(acc[tmi][tn][r]);
                    }
        } else {
            // V transposed sVt[c][tok]: r spans 4 consecutive tokens -> packed b64
            #pragma unroll
            for (int tmi = 0; tmi < 2; ++tmi)
                #pragma unroll
                for (int tn = 0; tn < 2; ++tn) {
                    int crow = 32 * w + 16 * tn + lr;
                    int tok0 = 32 * h + 16 * tmi + 4 * lg;
                    uint2 pk;
                    pk.x = pk2(acc[tmi][tn][0], acc[tmi][tn][1]);
                    pk.y = pk2(acc[tmi][tn][2], acc[tmi][tn][3]);
                    *(uint2*)(sVt + crow * 128 + ((2 * tok0) ^ ((crow & 7) << 4))) = pk;
                }
        }
    }
    __syncthreads();   // B2

    // ---- scores^T = mfma(A=K, B=Q): D[k=16tm+4lg+r][q=32h+16tq+lr] ----
    bf16x8 aK[4], bQ[2];
    const int colqk = (32 * w + 8 * lg) * 2;
    #pragma unroll
    for (int tm = 0; tm < 4; ++tm) {
        int row = 16 * tm + lr;
        aK[tm] = *(const bf16x8*)(sK + row * 256 + (colqk ^ ((row & 7) << 4)));
    }
    #pragma unroll
    for (int tq = 0; tq < 2; ++tq) {
        int row = 32 * h + 16 * tq + lr;
        bQ[tq] = *(const bf16x8*)(sQ + row * 256 + (colqk ^ ((row & 7) << 4)));
    }
    f32x4 sc[4][2];
    #pragma unroll
    for (int tm = 0; tm < 4; ++tm)
        #pragma unroll
        for (int tq = 0; tq < 2; ++tq) {
            sc[tm][tq] = (f32x4){0.f, 0.f, 0.f, 0.f};
            sc[tm][tq] = __builtin_amdgcn_mfma_f32_16x16x32_bf16(
                aK[tm], bQ[tq], sc[tm][tq], 0, 0, 0);
        }

    // ---- softmax: k lives in (tm,r) in-lane (16 vals) + lg across lanes ----
    const float scale = 0.17677669529663687f;   // 1/sqrt(32)
    const float L2E = 1.4426950408889634f;
    #pragma unroll
    for (int tq = 0; tq < 2; ++tq) {
        int q = 32 * h + 16 * tq + lr;
        #pragma unroll
        for (int tm = 0; tm < 4; ++tm) {
            float4 bb = *(const float4*)(Bb + q * 64 + 16 * tm + 4 * lg);
            sc[tm][tq][0] = sc[tm][tq][0] * scale + bb.x;
            sc[tm][tq][1] = sc[tm][tq][1] * scale + bb.y;
            sc[tm][tq][2] = sc[tm][tq][2] * scale + bb.z;
            sc[tm][tq][3] = sc[tm][tq][3] * scale + bb.w;
        }
        float mx = sc[0][tq][0];
        #pragma unroll
        for (int tm = 0; tm < 4; ++tm)
            #pragma unroll
            for (int r = 0; r < 4; ++r)
                mx = fmaxf(mx, sc[tm][tq][r]);
        mx = fmaxf(mx, __shfl_xor(mx, 16));
        mx = fmaxf(mx, __shfl_xor(mx, 32));
        float s = 0.f;
        #pragma unroll
        for (int tm = 0; tm < 4; ++tm)
            #pragma unroll
            for (int r = 0; r < 4; ++r) {
                float e = exp2f((sc[tm][tq][r] - mx) * L2E);
                sc[tm][tq][r] = e;
                s += e;
            }
        s += __shfl_xor(s, 16);
        s += __shfl_xor(s, 32);
        float rs = 1.0f / s;
        #pragma unroll
        for (int tm = 0; tm < 4; ++tm)
            #pragma unroll
            for (int r = 0; r < 4; ++r)
                sc[tm][tq][r] *= rs;        // normalize at source
    }
    __syncthreads();   // B3: sQ/sK frag reads done before sP overwrite

    // ---- P (normalized, bf16) -> per-wave-private sP rows, packed b64 ----
    char* sPw = sP + w * 8192;
    #pragma unroll
    for (int tm = 0; tm < 4; ++tm)
        #pragma unroll
        for (int tq = 0; tq < 2; ++tq) {
            int q = 32 * h + 16 * tq + lr;
            int k0 = 16 * tm + 4 * lg;
            uint2 pk;
            pk.x = pk2(sc[tm][tq][0], sc[tm][tq][1]);
            pk.y = pk2(sc[tm][tq][2], sc[tm][tq][3]);
            *(uint2*)(sPw + q * 128 + ((2 * k0) ^ ((q & 7) << 4))) = pk;
        }
    // same-wave write->read: compiler orders via lgkmcnt, no barrier needed

    // ---- out = P . V : q 32 (2 tiles), d 32 (2 tiles), K = 64 keys ----
    f32x4 o[2][2];
    #pragma unroll
    for (int tm2 = 0; tm2 < 2; ++tm2)
        #pragma unroll
        for (int tn = 0; tn < 2; ++tn)
            o[tm2][tn] = (f32x4){0.f, 0.f, 0.f, 0.f};
    #pragma unroll
    for (int kk = 0; kk < 2; ++kk) {
        bf16x8 aP[2], bV[2];
        int colk = (32 * kk + 8 * lg) * 2;
        #pragma unroll
        for (int tm2 = 0; tm2 < 2; ++tm2) {
            int q = 32 * h + 16 * tm2 + lr;
            aP[tm2] = *(const bf16x8*)(sPw + q * 128 + (colk ^ ((q & 7) << 4)));
        }
        #pragma unroll
        for (int tn = 0; tn < 2; ++tn) {
            int cc = 32 * w + 16 * tn + lr;
            bV[tn] = *(const bf16x8*)(sVt + cc * 128 + (colk ^ ((cc & 7) << 4)));
        }
        #pragma unroll
        for (int tm2 = 0; tm2 < 2; ++tm2)
            #pragma unroll
            for (int tn = 0; tn < 2; ++tn)
                o[tm2][tn] = __builtin_amdgcn_mfma_f32_16x16x32_bf16(
                    aP[tm2], bV[tn], o[tm2][tn], 0, 0, 0);
    }

    // ---- direct coalesced float4 stores (4 consecutive tokens per reg) ----
    #pragma unroll
    for (int tm2 = 0; tm2 < 2; ++tm2)
        #pragma unroll
        for (int tn = 0; tn < 2; ++tn) {
            int ch = 32 * w + 16 * tn + lr;
            int tok = 32 * h + 16 * tm2 + 4 * lg;
            float4 ov;
            ov.x = o[tm2][tn][0];
            ov.y = o[tm2][tn][1];
            ov.z = o[tm2][tn][2];
            ov.w = o[tm2][tn][3];
            *(float4*)(out + xbase + (long)ch * 16384 + tok) = ov;
        }
}

extern "C" void kernel_launch(void* const* d_in, const int* in_sizes, int n_in,
                              void* d_out, int out_size, void* d_ws, size_t ws_size,
                              hipStream_t stream) {
    const float* x  = (const float*)d_in[0];
    const float* Wq = (const float*)d_in[1];
    const float* bq = (const float*)d_in[2];
    const float* Wk = (const float*)d_in[3];
    const float* bk = (const float*)d_in[4];
    const float* Wv = (const float*)d_in[5];
    const float* bv = (const float*)d_in[6];
    const float* Bb = (const float*)d_in[7];
    float* out = (float*)d_out;
    ushort* wbf = (ushort*)d_ws;   // 3 x 128x128 bf16 = 96 KB

    wconv<<<64, 256, 0, stream>>>(Wq, Wk, Wv, wbf);
    attn_win<<<4096, 512, 0, stream>>>(x, wbf, bq, bk, bv, Bb, out);
}